// Round 1
// baseline (4980.236 us; speedup 1.0000x reference)
//
#include <hip/hip_runtime.h>

// SpikingLinearLayer: spikes = LIF_scan(x @ W^T)
//   x: [T=20, B=1024, IN=2048] fp32 (binary 0/1 spike trains)
//   W: [OUT=2048, IN=2048] fp32
//   out: [T, B, OUT] fp32 (binary spikes)
//
// Numerics: the t=0 spike decision is V = 0.05*cur vs 1.0 with cur ~ 20.5 +- 2
// -> centered exactly on the threshold. fp32 GEMM noise (~1e-5) flips O(1-10)
// decisions vs an fp64 reference -> absmax 1.0 fail. So all accumulation (GEMM
// and LIF state) is fp64: products of fp32 inputs are exact in fp64, total sum
// error ~1e-13, flip probability ~3e-7.

constexpr int T_STEPS = 20;
constexpr int BATCH   = 1024;
constexpr int NIN     = 2048;
constexpr int NOUT    = 2048;

constexpr int TB  = 64;      // batch tile per block
constexpr int TO  = 64;      // out tile per block
constexpr int KC  = 64;      // k-chunk staged in LDS
constexpr int LDP = KC + 1;  // +1 pad: kills the 16-way same-bank pattern

__global__ __launch_bounds__(256, 2)
void snn_fused(const float* __restrict__ x,
               const float* __restrict__ w,
               float* __restrict__ out)
{
    const int o0  = blockIdx.x * TO;
    const int b0  = blockIdx.y * TB;
    const int tid = threadIdx.x;
    const int tx  = tid & 15;   // out-group  (thread covers o = o0 + tx*4 + j)
    const int ty  = tid >> 4;   // batch-group(thread covers b = b0 + ty*4 + i)

    __shared__ float xs[TB][LDP];
    __shared__ float ws[TO][LDP];

    // staging assignment: 4 threads per row, 16 consecutive floats each
    const int lr = tid >> 2;         // 0..63 row
    const int lc = (tid & 3) << 4;   // 0,16,32,48

    double V[4][4], I[4][4];
#pragma unroll
    for (int i = 0; i < 4; ++i)
#pragma unroll
        for (int j = 0; j < 4; ++j) { V[i][j] = 0.0; I[i][j] = 0.0; }

    const double alpha_m = 1.0 - 1.0 / 20.0;  // 0.95
    const double alpha_s = 1.0 - 1.0 / 5.0;   // 0.8
    const double dtm     = 1.0 / 20.0;        // 0.05

    for (int t = 0; t < T_STEPS; ++t) {
        const float* xt = x + (size_t)t * BATCH * NIN;

        double c[4][4];
#pragma unroll
        for (int i = 0; i < 4; ++i)
#pragma unroll
            for (int j = 0; j < 4; ++j) c[i][j] = 0.0;

        for (int kc = 0; kc < NIN; kc += KC) {
            __syncthreads();
            {
                const float4* xg = reinterpret_cast<const float4*>(
                    xt + (size_t)(b0 + lr) * NIN + kc + lc);
                const float4* wg = reinterpret_cast<const float4*>(
                    w + (size_t)(o0 + lr) * NIN + kc + lc);
#pragma unroll
                for (int q = 0; q < 4; ++q) {
                    float4 xv = xg[q];
                    float4 wv = wg[q];
                    const int cb = lc + q * 4;
                    xs[lr][cb + 0] = xv.x;
                    xs[lr][cb + 1] = xv.y;
                    xs[lr][cb + 2] = xv.z;
                    xs[lr][cb + 3] = xv.w;
                    ws[lr][cb + 0] = wv.x;
                    ws[lr][cb + 1] = wv.y;
                    ws[lr][cb + 2] = wv.z;
                    ws[lr][cb + 3] = wv.w;
                }
            }
            __syncthreads();

#pragma unroll 8
            for (int k = 0; k < KC; ++k) {
                float xa[4], wa[4];
#pragma unroll
                for (int i = 0; i < 4; ++i) xa[i] = xs[ty * 4 + i][k];
#pragma unroll
                for (int j = 0; j < 4; ++j) wa[j] = ws[tx * 4 + j][k];
#pragma unroll
                for (int i = 0; i < 4; ++i)
#pragma unroll
                    for (int j = 0; j < 4; ++j)
                        c[i][j] += (double)xa[i] * (double)wa[j];
            }
        }

        // LIF update + spike emit for this timestep
#pragma unroll
        for (int i = 0; i < 4; ++i) {
            float sv[4];
#pragma unroll
            for (int j = 0; j < 4; ++j) {
                I[i][j] = alpha_s * I[i][j] + c[i][j];
                V[i][j] = alpha_m * V[i][j] + dtm * I[i][j];
                const double s = (V[i][j] >= 1.0) ? 1.0 : 0.0;
                V[i][j] *= (1.0 - s);
                sv[j] = (float)s;
            }
            const size_t oidx = (size_t)t * BATCH * NOUT
                              + (size_t)(b0 + ty * 4 + i) * NOUT
                              + (size_t)(o0 + tx * 4);
            *reinterpret_cast<float4*>(out + oidx) =
                make_float4(sv[0], sv[1], sv[2], sv[3]);
        }
    }
}

extern "C" void kernel_launch(void* const* d_in, const int* in_sizes, int n_in,
                              void* d_out, int out_size, void* d_ws, size_t ws_size,
                              hipStream_t stream) {
    const float* x = (const float*)d_in[0];
    const float* w = (const float*)d_in[1];
    float* out     = (float*)d_out;
    (void)d_ws; (void)ws_size; (void)in_sizes; (void)n_in; (void)out_size;

    dim3 grid(NOUT / TO, BATCH / TB);  // (32, 16)
    snn_fused<<<grid, dim3(256), 0, stream>>>(x, w, out);
}

// Round 3
// 858.868 us; speedup vs baseline: 5.7986x; 5.7986x over previous
//
#include <hip/hip_runtime.h>
#include <stdint.h>

// SpikingLinearLayer: spikes = LIF_scan(x @ W^T)
//   x: [20, 1024, 2048] fp32 binary; W: [2048, 2048] fp32; out fp32 binary.
//
// Exact-integer path: x is 0/1, so cur = subset-sum of W. Decompose
// round(W * 2^38) into Q=5 signed base-256 digits (int8 planes). Each digit
// plane GEMM runs on mfma_i32_16x16x64_i8 with EXACT i32 accumulation
// (|D_j| <= 2048*128 < 2^19). Recombine sum_j D_j*256^j in fp64 (< 2^50,
// exact), scale by 2^-38 (exact). Truncation <= 2^-39 per weight -> V error
// sigma ~1e-11, far below decision margins (fp64-equivalent). LIF in fp64.
//
// f64 MFMA (R2) failed: its 1-elem/lane fragment layout is unverified and
// evidently differs. i8 16x16 layouts ARE in the HW-verified set, and any
// within-fragment k permutation cancels (same formula used for A and B).
//
// Scratch: x as i8 (40 MB) + 5 limb planes (20 MB) = 60 MB in d_ws, rebuilt
// every call. If ws_size is too small, fall back to the verified R1 fp64
// VALU kernel (slow but correct).

constexpr int T_STEPS = 20;
constexpr int BATCH   = 1024;
constexpr int NIN     = 2048;
constexpr int NOUT    = 2048;

constexpr int    Q         = 5;                    // i8 limbs
constexpr double SCALE     = 274877906944.0;       // 2^38
constexpr double INV_SCALE = 1.0 / SCALE;          // 2^-38

constexpr size_t XI8_BYTES   = (size_t)T_STEPS * BATCH * NIN;  // 41943040
constexpr size_t PLANE_BYTES = (size_t)NOUT * NIN;             // 4194304
constexpr size_t WS_NEEDED   = XI8_BYTES + (size_t)Q * PLANE_BYTES;  // 62914560

typedef int v4i __attribute__((ext_vector_type(4)));

// ---------------------------------------------------------------- prep: x -> i8
__global__ void prep_x(const float* __restrict__ x, int8_t* __restrict__ xi) {
    const int idx = blockIdx.x * blockDim.x + threadIdx.x;   // one float4 each
    const float4 v = reinterpret_cast<const float4*>(x)[idx];
    char4 c;
    c.x = (char)(v.x != 0.0f);
    c.y = (char)(v.y != 0.0f);
    c.z = (char)(v.z != 0.0f);
    c.w = (char)(v.w != 0.0f);
    reinterpret_cast<char4*>(xi)[idx] = c;
}

// ------------------------------------------------- prep: W -> 5 base-256 digits
__global__ void prep_limbs(const float* __restrict__ w, int8_t* __restrict__ limbs) {
    const int idx = blockIdx.x * blockDim.x + threadIdx.x;   // 0 .. NOUT*NIN-1
    long long M = llrint((double)w[idx] * SCALE);            // |M| < 2^38
#pragma unroll
    for (int j = 0; j < Q - 1; ++j) {
        const int d = (int)((M + 128) & 255) - 128;          // signed digit
        limbs[(size_t)j * PLANE_BYTES + idx] = (int8_t)d;
        M = (M - d) >> 8;                                    // exact
    }
    limbs[(size_t)(Q - 1) * PLANE_BYTES + idx] = (int8_t)M;  // |top| <= ~65
}

// --------------------------------------------------------------- hot: i8 GEMMs
constexpr int KC   = 64;   // k bytes staged per chunk
constexpr int ROWB = 80;   // LDS row pitch (64 + 16 pad)

__global__ __launch_bounds__(256, 2)
void snn_i8(const int8_t* __restrict__ xi, const int8_t* __restrict__ limbs,
            float* __restrict__ out)
{
    // XCD-aware swizzle: 64 consecutive-round-robin blocks per XCD share 4
    // o-tiles -> limb working set 4*2048*5 = 2.6 MB fits the 4 MiB XCD L2.
    const int bid   = blockIdx.x;
    const int xcd   = bid & 7;
    const int sub   = bid >> 3;                 // 0..63
    const int otile = xcd * 4 + (sub & 3);      // 0..31
    const int btile = sub >> 2;                 // 0..15
    const int o0 = otile * 64, b0 = btile * 64;

    const int tid = threadIdx.x;
    const int wvid = tid >> 6;      // wave id -> o j-block (16 cols)
    const int ln   = tid & 63;
    const int lm   = ln & 15;       // A row-in-group / B col-in-group
    const int qd   = ln >> 4;       // k-quad / D row-subgroup

    __shared__ __align__(16) int8_t xs[64 * ROWB];
    __shared__ __align__(16) int8_t ls[Q][64 * ROWB];

    const int sr = tid >> 2;          // staging row 0..63
    const int sc = (tid & 3) * 16;    // staging byte col 0/16/32/48

    // lane's LIF elements e = mg*4 + r:
    //   b = b0 + 16*mg + 4*qd + r,  o = o0 + 16*wvid + lm
    double V[16], I[16];
#pragma unroll
    for (int e = 0; e < 16; ++e) { V[e] = 0.0; I[e] = 0.0; }

    const double alpha_m = 1.0 - 1.0 / 20.0;
    const double alpha_s = 1.0 - 1.0 / 5.0;
    const double dtm     = 1.0 / 20.0;

    for (int t = 0; t < T_STEPS; ++t) {
        v4i acc[4][Q];
#pragma unroll
        for (int mg = 0; mg < 4; ++mg)
#pragma unroll
            for (int j = 0; j < Q; ++j) acc[mg][j] = (v4i){0, 0, 0, 0};

        const int8_t* xt = xi + (size_t)t * BATCH * NIN;

        for (int kc = 0; kc < NIN; kc += KC) {
            __syncthreads();
            // stage x chunk [64 b][64 k] and 5 limb chunks [64 o][64 k]
            *reinterpret_cast<v4i*>(&xs[sr * ROWB + sc]) =
                *reinterpret_cast<const v4i*>(&xt[(size_t)(b0 + sr) * NIN + kc + sc]);
#pragma unroll
            for (int j = 0; j < Q; ++j) {
                *reinterpret_cast<v4i*>(&ls[j][sr * ROWB + sc]) =
                    *reinterpret_cast<const v4i*>(
                        &limbs[(size_t)j * PLANE_BYTES + (size_t)(o0 + sr) * NIN + kc + sc]);
            }
            __syncthreads();

            v4i a[4];
#pragma unroll
            for (int mg = 0; mg < 4; ++mg)
                a[mg] = *reinterpret_cast<const v4i*>(&xs[(16 * mg + lm) * ROWB + qd * 16]);

#pragma unroll
            for (int j = 0; j < Q; ++j) {
                const v4i b = *reinterpret_cast<const v4i*>(
                    &ls[j][(16 * wvid + lm) * ROWB + qd * 16]);
#pragma unroll
                for (int mg = 0; mg < 4; ++mg)
                    acc[mg][j] = __builtin_amdgcn_mfma_i32_16x16x64_i8(
                        a[mg], b, acc[mg][j], 0, 0, 0);
            }
        }

        // recombine digits (exact in fp64), LIF update, emit spikes
        const int ocol = o0 + 16 * wvid + lm;
#pragma unroll
        for (int mg = 0; mg < 4; ++mg) {
#pragma unroll
            for (int r = 0; r < 4; ++r) {
                double s = (double)acc[mg][Q - 1][r];
#pragma unroll
                for (int j = Q - 2; j >= 0; --j)
                    s = s * 256.0 + (double)acc[mg][j][r];
                const double cur = s * INV_SCALE;

                const int e = mg * 4 + r;
                I[e] = alpha_s * I[e] + cur;
                V[e] = alpha_m * V[e] + dtm * I[e];
                const double sp = (V[e] >= 1.0) ? 1.0 : 0.0;
                V[e] *= (1.0 - sp);

                const int brow = b0 + 16 * mg + 4 * qd + r;
                out[(size_t)t * BATCH * NOUT + (size_t)brow * NOUT + ocol] = (float)sp;
            }
        }
    }
}

// ------------------------------------------------ fallback: verified R1 kernel
constexpr int TBF = 64, TOF = 64, KCF = 64, LDPF = KCF + 4;

__global__ __launch_bounds__(256, 2)
void snn_fused(const float* __restrict__ x,
               const float* __restrict__ w,
               float* __restrict__ out)
{
    const int o0  = blockIdx.x * TOF;
    const int b0  = blockIdx.y * TBF;
    const int tid = threadIdx.x;
    const int tx  = tid & 15;
    const int ty  = tid >> 4;

    __shared__ float xs[TBF][LDPF];
    __shared__ float ws[TOF][LDPF];

    const int lr = tid >> 2;
    const int lc = (tid & 3) << 4;

    double V[4][4], I[4][4];
#pragma unroll
    for (int i = 0; i < 4; ++i)
#pragma unroll
        for (int j = 0; j < 4; ++j) { V[i][j] = 0.0; I[i][j] = 0.0; }

    const double alpha_m = 1.0 - 1.0 / 20.0;
    const double alpha_s = 1.0 - 1.0 / 5.0;
    const double dtm     = 1.0 / 20.0;

    for (int t = 0; t < T_STEPS; ++t) {
        const float* xt = x + (size_t)t * BATCH * NIN;

        double c[4][4];
#pragma unroll
        for (int i = 0; i < 4; ++i)
#pragma unroll
            for (int j = 0; j < 4; ++j) c[i][j] = 0.0;

        for (int kc = 0; kc < NIN; kc += KCF) {
            __syncthreads();
            {
                const float4* xg = reinterpret_cast<const float4*>(
                    xt + (size_t)(b0 + lr) * NIN + kc + lc);
                const float4* wg = reinterpret_cast<const float4*>(
                    w + (size_t)(o0 + lr) * NIN + kc + lc);
#pragma unroll
                for (int q = 0; q < 4; ++q) {
                    float4 xv = xg[q];
                    float4 wv4 = wg[q];
                    const int cb = lc + q * 4;
                    xs[lr][cb + 0] = xv.x;  xs[lr][cb + 1] = xv.y;
                    xs[lr][cb + 2] = xv.z;  xs[lr][cb + 3] = xv.w;
                    ws[lr][cb + 0] = wv4.x; ws[lr][cb + 1] = wv4.y;
                    ws[lr][cb + 2] = wv4.z; ws[lr][cb + 3] = wv4.w;
                }
            }
            __syncthreads();

#pragma unroll 8
            for (int k = 0; k < KCF; ++k) {
                float xa[4], wa[4];
#pragma unroll
                for (int i = 0; i < 4; ++i) xa[i] = xs[ty * 4 + i][k];
#pragma unroll
                for (int j = 0; j < 4; ++j) wa[j] = ws[tx * 4 + j][k];
#pragma unroll
                for (int i = 0; i < 4; ++i)
#pragma unroll
                    for (int j = 0; j < 4; ++j)
                        c[i][j] += (double)xa[i] * (double)wa[j];
            }
        }

#pragma unroll
        for (int i = 0; i < 4; ++i) {
            float sv[4];
#pragma unroll
            for (int j = 0; j < 4; ++j) {
                I[i][j] = alpha_s * I[i][j] + c[i][j];
                V[i][j] = alpha_m * V[i][j] + dtm * I[i][j];
                const double s = (V[i][j] >= 1.0) ? 1.0 : 0.0;
                V[i][j] *= (1.0 - s);
                sv[j] = (float)s;
            }
            const size_t oidx = (size_t)t * BATCH * NOUT
                              + (size_t)(b0 + ty * 4 + i) * NOUT
                              + (size_t)(o0 + tx * 4);
            *reinterpret_cast<float4*>(out + oidx) =
                make_float4(sv[0], sv[1], sv[2], sv[3]);
        }
    }
}

extern "C" void kernel_launch(void* const* d_in, const int* in_sizes, int n_in,
                              void* d_out, int out_size, void* d_ws, size_t ws_size,
                              hipStream_t stream) {
    const float* x = (const float*)d_in[0];
    const float* w = (const float*)d_in[1];
    float* out     = (float*)d_out;
    (void)in_sizes; (void)n_in; (void)out_size;

    if (ws_size >= WS_NEEDED) {
        int8_t* xi    = (int8_t*)d_ws;
        int8_t* limbs = xi + XI8_BYTES;
        prep_x<<<(T_STEPS * BATCH * NIN / 4) / 256, 256, 0, stream>>>(x, xi);
        prep_limbs<<<(NOUT * NIN) / 256, 256, 0, stream>>>(w, limbs);
        snn_i8<<<512, 256, 0, stream>>>(xi, limbs, out);
    } else {
        dim3 grid(NOUT / TOF, BATCH / TBF);
        snn_fused<<<grid, dim3(256), 0, stream>>>(x, w, out);
    }
}

// Round 4
// 715.287 us; speedup vs baseline: 6.9626x; 1.2007x over previous
//
#include <hip/hip_runtime.h>
#include <stdint.h>

// SpikingLinearLayer: spikes = LIF_scan(x @ W^T)  -- exact i8-limb MFMA path.
//   x: [20, 1024, 2048] fp32 binary; W: [2048, 2048] fp32; out fp32 binary.
//
// R3 -> R4:
//  * Q=5 -> 4 limbs (scale 2^30): quantization error ~4e-9 on V, flips ~3e-4
//    expected -> still fp64-equivalent for spike decisions. 20% less work.
//  * Conflict-free permuted LDS: fragments stored at slot (group*64+lane)*16,
//    so all ds_read_b128 / deposits are lane-contiguous. R3 lost 27% of
//    cycles to SQ_LDS_BANK_CONFLICT (ROWB=80 period-8 aliasing).
//  * Staging via __builtin_amdgcn_global_load_lds width=16 (async DMA,
//    uniform LDS base + lane*16 -- exactly the permuted layout).
//  * TT=2 timesteps per kc-sweep: limbs (t-invariant) staged once per t-pair;
//    i32 accs for both t persist across the kc loop (no overflow: <=2^18).
//  * Double-buffered LDS, ONE barrier per iter; DMA for iter s+1 issued
//    before compute of s, so the pre-barrier vmcnt drain is already hidden.

constexpr int T_STEPS = 20;
constexpr int BATCH   = 1024;
constexpr int NIN     = 2048;
constexpr int NOUT    = 2048;

constexpr int    Q         = 4;
constexpr double SCALE     = 1073741824.0;     // 2^30
constexpr double INV_SCALE = 1.0 / SCALE;

constexpr size_t XI8_BYTES   = (size_t)T_STEPS * BATCH * NIN;        // 40 MB
constexpr size_t PLANE_BYTES = (size_t)NOUT * NIN;                   // 4 MB
constexpr size_t WS_NEEDED   = XI8_BYTES + (size_t)Q * PLANE_BYTES;  // 56 MB

typedef int v4i __attribute__((ext_vector_type(4)));

// async 16B/lane global->LDS DMA: lds dst = uniform base + lane*16
__device__ __forceinline__ void dma16(const int8_t* g, const int8_t* l) {
    __builtin_amdgcn_global_load_lds(
        (const __attribute__((address_space(1))) void*)(uintptr_t)g,
        (__attribute__((address_space(3))) void*)(uint32_t)(uintptr_t)l,
        16, 0, 0);
}

// ---------------------------------------------------------------- prep: x -> i8
__global__ void prep_x(const float* __restrict__ x, int8_t* __restrict__ xi) {
    const int idx = blockIdx.x * blockDim.x + threadIdx.x;   // 16 elems each
    const float4* xg = reinterpret_cast<const float4*>(x) + idx * 4;
    int8_t c[16];
#pragma unroll
    for (int q = 0; q < 4; ++q) {
        const float4 v = xg[q];
        c[q * 4 + 0] = (int8_t)(v.x != 0.0f);
        c[q * 4 + 1] = (int8_t)(v.y != 0.0f);
        c[q * 4 + 2] = (int8_t)(v.z != 0.0f);
        c[q * 4 + 3] = (int8_t)(v.w != 0.0f);
    }
    reinterpret_cast<v4i*>(xi)[idx] = *reinterpret_cast<const v4i*>(c);
}

// ------------------------------------------------- prep: W -> 4 base-256 digits
__global__ void prep_limbs(const float* __restrict__ w, int8_t* __restrict__ limbs) {
    const int idx = blockIdx.x * blockDim.x + threadIdx.x;   // 4 weights each
    const float4 wv = reinterpret_cast<const float4*>(w)[idx];
    const float wf[4] = {wv.x, wv.y, wv.z, wv.w};
    int8_t d[Q][4];
#pragma unroll
    for (int e = 0; e < 4; ++e) {
        long long M = llrint((double)wf[e] * SCALE);         // |M| < 2^30
#pragma unroll
        for (int j = 0; j < Q - 1; ++j) {
            const int dj = (int)((M + 128) & 255) - 128;
            d[j][e] = (int8_t)dj;
            M = (M - dj) >> 8;                               // exact
        }
        d[Q - 1][e] = (int8_t)M;                             // |top| <= 65
    }
#pragma unroll
    for (int j = 0; j < Q; ++j)
        reinterpret_cast<char4*>(limbs + (size_t)j * PLANE_BYTES)[idx] =
            make_char4(d[j][0], d[j][1], d[j][2], d[j][3]);
}

// --------------------------------------------------------------- hot: i8 GEMMs
constexpr int KC     = 64;
constexpr int NKC    = NIN / KC;            // 32
constexpr int NTB    = T_STEPS / 2;         // 10 t-pairs
constexpr int NITER  = NTB * NKC;           // 320
constexpr int BUF_B  = 24576;               // A(2t)*4KB + B(4 planes)*4KB = 24KB
constexpr int A_OFF  = 0;                   // A[t] at t*4096
constexpr int B_OFF  = 8192;                // B[j] at 8192 + j*4096

__global__ __launch_bounds__(256, 2)
void snn_i8(const int8_t* __restrict__ xi, const int8_t* __restrict__ limbs,
            float* __restrict__ out)
{
    // XCD swizzle: 4 o-tiles pinned per XCD -> limb set 4*512KB = 2MB in 4MB L2
    const int bid   = blockIdx.x;
    const int xcd   = bid & 7;
    const int sub   = bid >> 3;
    const int otile = xcd * 4 + (sub & 3);
    const int btile = sub >> 2;
    const int o0 = otile * 64, b0 = btile * 64;

    const int tid  = threadIdx.x;
    const int w    = tid >> 6;     // wave id: o j-group for compute, stage group
    const int ln   = tid & 63;
    const int lm   = ln & 15;
    const int qd   = ln >> 4;

    __shared__ __align__(16) int8_t lds[2][BUF_B];

    // per-lane global byte offsets (lane ln deposits at base + ln*16)
    const size_t x_lane = (size_t)(b0 + 16 * w + lm) * NIN + qd * 16;
    const size_t l_lane = (size_t)(o0 + 16 * w + lm) * NIN + qd * 16;

    // LIF state: lane elems e = mg*4+r -> b = b0+16mg+4qd+r, o = o0+16w+lm
    double V[16], I[16];
#pragma unroll
    for (int e = 0; e < 16; ++e) { V[e] = 0.0; I[e] = 0.0; }

    const double alpha_m = 1.0 - 1.0 / 20.0;
    const double alpha_s = 1.0 - 1.0 / 5.0;
    const double dtm     = 1.0 / 20.0;

    // stage iter s into lds[s&1]; 6 DMAs per wave (A t0, A t1, B j=0..3)
    auto stage = [&](int s) {
        const int tb = s >> 5;
        const int kc = (s & 31) << 6;
        const int8_t* xb = xi + (size_t)(2 * tb) * BATCH * NIN + kc + x_lane;
        int8_t* lb = &lds[s & 1][0];
        dma16(xb,                         lb + A_OFF + 0    + w * 1024);
        dma16(xb + (size_t)BATCH * NIN,   lb + A_OFF + 4096 + w * 1024);
#pragma unroll
        for (int j = 0; j < Q; ++j)
            dma16(limbs + (size_t)j * PLANE_BYTES + kc + l_lane,
                  lb + B_OFF + j * 4096 + w * 1024);
    };

    stage(0);
    __syncthreads();

    int s = 0;
    for (int tb = 0; tb < NTB; ++tb) {
        v4i acc0[4][4], acc1[4][4];   // [mg][plane]
#pragma unroll
        for (int mg = 0; mg < 4; ++mg)
#pragma unroll
            for (int j = 0; j < Q; ++j) {
                acc0[mg][j] = (v4i){0, 0, 0, 0};
                acc1[mg][j] = (v4i){0, 0, 0, 0};
            }

        for (int kci = 0; kci < NKC; ++kci, ++s) {
            if (s + 1 < NITER) stage(s + 1);            // async prefetch

            const int8_t* cb = &lds[s & 1][0];
            v4i B[4];
#pragma unroll
            for (int j = 0; j < Q; ++j)
                B[j] = *reinterpret_cast<const v4i*>(
                    cb + B_OFF + j * 4096 + w * 1024 + ln * 16);
#pragma unroll
            for (int mg = 0; mg < 4; ++mg) {
                const v4i A0 = *reinterpret_cast<const v4i*>(
                    cb + A_OFF + 0    + mg * 1024 + ln * 16);
                const v4i A1 = *reinterpret_cast<const v4i*>(
                    cb + A_OFF + 4096 + mg * 1024 + ln * 16);
#pragma unroll
                for (int j = 0; j < Q; ++j) {
                    acc0[mg][j] = __builtin_amdgcn_mfma_i32_16x16x64_i8(
                        A0, B[j], acc0[mg][j], 0, 0, 0);
                    acc1[mg][j] = __builtin_amdgcn_mfma_i32_16x16x64_i8(
                        A1, B[j], acc1[mg][j], 0, 0, 0);
                }
            }
            __syncthreads();   // drains DMA (already landed under the MFMAs)
        }

        // recombine digits (exact fp64), LIF, emit spikes for t-pair
        const int ocol = o0 + 16 * w + lm;
#pragma unroll
        for (int tt = 0; tt < 2; ++tt) {
            const int t = 2 * tb + tt;
#pragma unroll
            for (int mg = 0; mg < 4; ++mg) {
#pragma unroll
                for (int r = 0; r < 4; ++r) {
                    const int d0 = tt ? acc1[mg][0][r] : acc0[mg][0][r];
                    const int d1 = tt ? acc1[mg][1][r] : acc0[mg][1][r];
                    const int d2 = tt ? acc1[mg][2][r] : acc0[mg][2][r];
                    const int d3 = tt ? acc1[mg][3][r] : acc0[mg][3][r];
                    double sm = (double)d3;
                    sm = sm * 256.0 + (double)d2;
                    sm = sm * 256.0 + (double)d1;
                    sm = sm * 256.0 + (double)d0;
                    const double cur = sm * INV_SCALE;

                    const int e = mg * 4 + r;
                    I[e] = alpha_s * I[e] + cur;
                    V[e] = alpha_m * V[e] + dtm * I[e];
                    const double sp = (V[e] >= 1.0) ? 1.0 : 0.0;
                    V[e] *= (1.0 - sp);

                    const int brow = b0 + 16 * mg + 4 * qd + r;
                    out[(size_t)t * BATCH * NOUT + (size_t)brow * NOUT + ocol]
                        = (float)sp;
                }
            }
        }
    }
}

// ------------------------------------------------ fallback: verified R1 kernel
constexpr int TBF = 64, TOF = 64, KCF = 64, LDPF = KCF + 4;

__global__ __launch_bounds__(256, 2)
void snn_fused(const float* __restrict__ x,
               const float* __restrict__ w,
               float* __restrict__ out)
{
    const int o0  = blockIdx.x * TOF;
    const int b0  = blockIdx.y * TBF;
    const int tid = threadIdx.x;
    const int tx  = tid & 15;
    const int ty  = tid >> 4;

    __shared__ float xs[TBF][LDPF];
    __shared__ float ws[TOF][LDPF];

    const int lr = tid >> 2;
    const int lc = (tid & 3) << 4;

    double V[4][4], I[4][4];
#pragma unroll
    for (int i = 0; i < 4; ++i)
#pragma unroll
        for (int j = 0; j < 4; ++j) { V[i][j] = 0.0; I[i][j] = 0.0; }

    const double alpha_m = 1.0 - 1.0 / 20.0;
    const double alpha_s = 1.0 - 1.0 / 5.0;
    const double dtm     = 1.0 / 20.0;

    for (int t = 0; t < T_STEPS; ++t) {
        const float* xt = x + (size_t)t * BATCH * NIN;
        double c[4][4];
#pragma unroll
        for (int i = 0; i < 4; ++i)
#pragma unroll
            for (int j = 0; j < 4; ++j) c[i][j] = 0.0;

        for (int kc = 0; kc < NIN; kc += KCF) {
            __syncthreads();
            {
                const float4* xg = reinterpret_cast<const float4*>(
                    xt + (size_t)(b0 + lr) * NIN + kc + lc);
                const float4* wg = reinterpret_cast<const float4*>(
                    w + (size_t)(o0 + lr) * NIN + kc + lc);
#pragma unroll
                for (int q = 0; q < 4; ++q) {
                    float4 xv = xg[q];
                    float4 wv4 = wg[q];
                    const int cbi = lc + q * 4;
                    xs[lr][cbi + 0] = xv.x;  xs[lr][cbi + 1] = xv.y;
                    xs[lr][cbi + 2] = xv.z;  xs[lr][cbi + 3] = xv.w;
                    ws[lr][cbi + 0] = wv4.x; ws[lr][cbi + 1] = wv4.y;
                    ws[lr][cbi + 2] = wv4.z; ws[lr][cbi + 3] = wv4.w;
                }
            }
            __syncthreads();

#pragma unroll 8
            for (int k = 0; k < KCF; ++k) {
                float xa[4], wa[4];
#pragma unroll
                for (int i = 0; i < 4; ++i) xa[i] = xs[ty * 4 + i][k];
#pragma unroll
                for (int j = 0; j < 4; ++j) wa[j] = ws[tx * 4 + j][k];
#pragma unroll
                for (int i = 0; i < 4; ++i)
#pragma unroll
                    for (int j = 0; j < 4; ++j)
                        c[i][j] += (double)xa[i] * (double)wa[j];
            }
        }

#pragma unroll
        for (int i = 0; i < 4; ++i) {
            float sv[4];
#pragma unroll
            for (int j = 0; j < 4; ++j) {
                I[i][j] = alpha_s * I[i][j] + c[i][j];
                V[i][j] = alpha_m * V[i][j] + dtm * I[i][j];
                const double sp = (V[i][j] >= 1.0) ? 1.0 : 0.0;
                V[i][j] *= (1.0 - sp);
                sv[j] = (float)sp;
            }
            const size_t oidx = (size_t)t * BATCH * NOUT
                              + (size_t)(b0 + ty * 4 + i) * NOUT
                              + (size_t)(o0 + tx * 4);
            *reinterpret_cast<float4*>(out + oidx) =
                make_float4(sv[0], sv[1], sv[2], sv[3]);
        }
    }
}

extern "C" void kernel_launch(void* const* d_in, const int* in_sizes, int n_in,
                              void* d_out, int out_size, void* d_ws, size_t ws_size,
                              hipStream_t stream) {
    const float* x = (const float*)d_in[0];
    const float* w = (const float*)d_in[1];
    float* out     = (float*)d_out;
    (void)in_sizes; (void)n_in; (void)out_size;

    if (ws_size >= WS_NEEDED) {
        int8_t* xi    = (int8_t*)d_ws;
        int8_t* limbs = xi + XI8_BYTES;
        prep_x<<<(int)(XI8_BYTES / 16 / 256), 256, 0, stream>>>(x, xi);
        prep_limbs<<<(int)(PLANE_BYTES / 4 / 256), 256, 0, stream>>>(w, limbs);
        snn_i8<<<512, 256, 0, stream>>>(xi, limbs, out);
    } else {
        dim3 grid(NOUT / TOF, BATCH / TBF);
        snn_fused<<<grid, dim3(256), 0, stream>>>(x, w, out);
    }
}